// Round 8
// baseline (96.023 us; speedup 1.0000x reference)
//
#include <hip/hip_runtime.h>
#include <math.h>

#define BB 1024
#define TT 500
#define CC_ 64
#define KK 2000

#define LOG2E 1.44269504088896340736f
#define LN2   0.69314718055994530942f

// ---- fast hardware exp2/log2 (v_exp_f32 / v_log_f32) ----
#if __has_builtin(__builtin_amdgcn_exp2f)
__device__ __forceinline__ float fast_exp2(float x) { return __builtin_amdgcn_exp2f(x); }
#else
__device__ __forceinline__ float fast_exp2(float x) { return exp2f(x); }
#endif
#if __has_builtin(__builtin_amdgcn_logf)
__device__ __forceinline__ float fast_log2(float x) { return __builtin_amdgcn_logf(x); }
#else
__device__ __forceinline__ float fast_log2(float x) { return log2f(x); }
#endif

#if __has_builtin(__builtin_amdgcn_sched_barrier)
#define SCHED_FENCE() __builtin_amdgcn_sched_barrier(0)
#else
#define SCHED_FENCE()
#endif

// max-guarded log2-sum-exp2 (off the hot loop)
__device__ __forceinline__ float lse2_2(float a, float b) {
    float m = fmaxf(a, b);
    float d = fminf(a, b) - m;              // <= 0
    return m + fast_log2(1.0f + fast_exp2(d));
}

// ---- DPP adds (VALU pipe, no LDS) ----
template<int CTRL, int RM, int BM>
__device__ __forceinline__ float dpp_add(float x) {
    int s = __builtin_amdgcn_update_dpp(0, __float_as_int(x), CTRL, RM, BM, true);
    return x + __int_as_float(s);
}
// full 64-lane sum into lane 63 (precompute only)
__device__ __forceinline__ float wave_sum63(float x) {
    x = dpp_add<0x111, 0xf, 0xf>(x);  // row_shr:1
    x = dpp_add<0x112, 0xf, 0xf>(x);  // row_shr:2
    x = dpp_add<0x114, 0xf, 0xf>(x);  // row_shr:4
    x = dpp_add<0x118, 0xf, 0xf>(x);  // row_shr:8
    x = dpp_add<0x142, 0xa, 0xf>(x);  // row_bcast15 (rows 1,3)
    x = dpp_add<0x143, 0xc, 0xf>(x);  // row_bcast31 (rows 2,3)
    return x;
}
// sum over the 16-lane DPP row; result in EVERY lane of the row (rotations)
__device__ __forceinline__ float rowsum16(float x) {
    x = dpp_add<0x121, 0xf, 0xf>(x);  // row_ror:1
    x = dpp_add<0x122, 0xf, 0xf>(x);  // row_ror:2
    x = dpp_add<0x124, 0xf, 0xf>(x);  // row_ror:4
    x = dpp_add<0x128, 0xf, 0xf>(x);  // row_ror:8
    return x;
}

// Precompute per-k tables (log2 units):
//   PA[k]    = {a1[0][0], a1[0][1], a1[1][0], a1[1][1]}         (for finish_py)
//   P3[k][y] = {2^(sel0+q00), 2^(sel0+q10), sel1+q01, sel1+q11} (for bkt_main)
__global__ __launch_bounds__(64) void precompute_P(
    const float* __restrict__ A,
    const float* __restrict__ trans_logits,
    const float* __restrict__ obs_logits,
    float* __restrict__ PA,
    float* __restrict__ P3)
{
    int k = blockIdx.x;
    int c = threadIdx.x;  // 0..63

    float ob[2][2];
#pragma unroll
    for (int s = 0; s < 2; ++s) {
        float o0 = obs_logits[c * 4 + s * 2 + 0] * LOG2E;
        float o1 = obs_logits[c * 4 + s * 2 + 1] * LOG2E;
        float l = lse2_2(o0, o1);
        ob[s][0] = o0 - l;
        ob[s][1] = o1 - l;
    }
    float lt[2][2];
    {
        float t00 = trans_logits[c * 4 + 0] * LOG2E;
        float t01 = trans_logits[c * 4 + 1] * LOG2E;
        float t10 = trans_logits[c * 4 + 2] * LOG2E;
        float t11 = trans_logits[c * 4 + 3] * LOG2E;
        float l0 = lse2_2(t00, t10);  // normalize over s (axis=1), u=0
        float l1 = lse2_2(t01, t11);  // u=1
        lt[0][0] = t00 - l0; lt[0][1] = t01 - l1;
        lt[1][0] = t10 - l0; lt[1][1] = t11 - l1;
    }

    float a = A[k * CC_ + c];
    float v[8];
    v[0] = a * ob[0][0]; v[1] = a * ob[0][1];
    v[2] = a * ob[1][0]; v[3] = a * ob[1][1];
    v[4] = a * lt[0][0]; v[5] = a * lt[0][1];
    v[6] = a * lt[1][0]; v[7] = a * lt[1][1];

#pragma unroll
    for (int i = 0; i < 8; ++i) v[i] = wave_sum63(v[i]);
    if (c == 63) {
        ((float4*)PA)[k] = make_float4(v[0], v[1], v[2], v[3]);
#pragma unroll
        for (int y = 0; y < 2; ++y) {
            float sel0 = v[y];      // a1[0][y]
            float sel1 = v[2 + y];  // a1[1][y]
            ((float4*)P3)[k * 2 + y] = make_float4(
                fast_exp2(sel0 + v[4]),   // E0 = 2^(sel0+q00)
                fast_exp2(sel0 + v[6]),   // E1 = 2^(sel0+q10)
                sel1 + v[5],              // v0 = sel1+q01
                sel1 + v[7]);             // v1 = sel1+q11
        }
    }
}

// Serial forward pass, 4 batches per wave (group g = lane>>4, lane i = lane&15
// holds chains 4i..4i+3). Rings: k/y depth 16 (loaded 16 ahead), A/P3 depth 8
// at prefetch distance 6. KEY (round 8): __builtin_amdgcn_sched_barrier(0)
// between each step's load-issue section and its compute section — without it
// the scheduler sinks the prefetch loads down to their uses (observed VGPR=56
// < ring size), collapsing the pipeline and exposing a full L2 round trip on
// every step (measured 410 cy/step, VALUBusy 13%). The fence forces the
// 6-step liveness; compiler-inserted partial vmcnt waits are then already
// satisfied in steady state.
__global__ __launch_bounds__(64) void bkt_main(
    const int* __restrict__ corr,
    const int* __restrict__ kc,
    const float* __restrict__ A,
    const float* __restrict__ init_logits,
    const float* __restrict__ P3,
    float* __restrict__ out)
{
    int lane = threadIdx.x;
    int g = lane >> 4, i = lane & 15;
    int b = blockIdx.x * 4 + g;

    float la[4][2];
#pragma unroll
    for (int j = 0; j < 4; ++j) {
        float i0 = init_logits[(4 * i + j) * 2 + 0] * LOG2E;
        float i1 = init_logits[(4 * i + j) * 2 + 1] * LOG2E;
        float l = lse2_2(i0, i1);
        la[j][0] = i0 - l;
        la[j][1] = i1 - l;
    }

    const int* kcb = kc + b * TT;
    const int* cb  = corr + b * TT;
    float2* outb   = (float2*)(out + (size_t)b * TT * 2);

    // k/y ring, depth 16 (slot m holds step tt+m)
    int kq[16], yq[16];
#pragma unroll
    for (int q = 0; q < 16; ++q) { kq[q] = kcb[q]; yq[q] = cb[q]; }

    // A-row / P3-row rings, depth 8; prefill steps 0..5 (prefetch distance 6)
    float4 ccq[8], pq[8];
#pragma unroll
    for (int q = 0; q < 6; ++q) {
        ccq[q] = *(const float4*)(A + kq[q] * CC_ + 4 * i);
        pq[q]  = ((const float4*)P3)[kq[q] * 2 + yq[q]];
    }

    // 32 blocks of 16 = 512 steps; t=500..511 are phantoms (clamped loads,
    // guarded store, discarded la updates on valid-but-stale data).
    for (int tt = 0; tt <= 496; tt += 16) {
#pragma unroll
        for (int j = 0; j < 16; ++j) {
            int t = tt + j;
            // ---- load-issue section ----
            // refill k/y slot j with step t+16 (clamped: no OOB)
            int t16 = t + 16; if (t16 > TT - 1) t16 = TT - 1;
            int knew = kcb[t16];
            int ynew = cb[t16];
            // prefetch A/P3 for step t+6 into slot (j+6)&7
            int kp = kq[(j + 6) & 15], yp = yq[(j + 6) & 15];
            ccq[(j + 6) & 7] = *(const float4*)(A + kp * CC_ + 4 * i);
            pq[(j + 6) & 7]  = ((const float4*)P3)[kp * 2 + yp];

            SCHED_FENCE();  // loads may not sink past this point

            // ---- compute section (consumes loads issued 6 steps ago) ----
            float4 cc = ccq[j & 7];
            float4 pr = pq[j & 7];
            kq[j] = knew; yq[j] = ynew;

            // r[s] = sum_c A[k,c]*la[c,s]: in-lane tree + 4 DPP rors
            float x0 = (cc.x * la[0][0] + cc.y * la[1][0])
                     + (cc.z * la[2][0] + cc.w * la[3][0]);
            float x1 = (cc.x * la[0][1] + cc.y * la[1][1])
                     + (cc.z * la[2][1] + cc.w * la[3][1]);
            x0 = rowsum16(x0);
            x1 = rowsum16(x1);
            if (t < TT && i == 0) outb[t] = make_float2(x0, x1);

            // tail: only d = r1-r0 enters; E/v precomputed per (k,y)
            float d   = x1 - x0;
            float a30 = fast_log2(pr.x + fast_exp2(pr.z + d));  // a3[0]-r0
            float a31 = fast_log2(pr.y + fast_exp2(pr.w + d));  // a3[1]-r0
            // la_new = (1-cc)*(la - r0) + cc*a3'  (renorm by -r0 built in)
            {
                float g0, g1;
                g0 = la[0][0] - x0; g1 = la[0][1] - x0;
                la[0][0] = g0 + cc.x * (a30 - g0);
                la[0][1] = g1 + cc.x * (a31 - g1);
                g0 = la[1][0] - x0; g1 = la[1][1] - x0;
                la[1][0] = g0 + cc.y * (a30 - g0);
                la[1][1] = g1 + cc.y * (a31 - g1);
                g0 = la[2][0] - x0; g1 = la[2][1] - x0;
                la[2][0] = g0 + cc.z * (a30 - g0);
                la[2][1] = g1 + cc.z * (a31 - g1);
                g0 = la[3][0] - x0; g1 = la[3][1] - x0;
                la[3][0] = g0 + cc.w * (a30 - g0);
                la[3][1] = g1 + cc.w * (a31 - g1);
            }
        }
    }
}

// Fully parallel epilogue: stored (r0,r1) -> log-softmax'd output (nat-log).
__global__ __launch_bounds__(256) void finish_py(
    const int* __restrict__ kc,
    const float* __restrict__ PA,
    float* __restrict__ out)
{
    int idx = blockIdx.x * 256 + threadIdx.x;  // idx = b*TT + t
    if (idx >= BB * TT) return;
    int k = kc[idx];
    float2 r  = ((const float2*)out)[idx];
    float4 pa = ((const float4*)PA)[k];
    float lo0 = lse2_2(pa.x + r.x, pa.z + r.y);  // log2 p(y=0) (shifted)
    float lo1 = lse2_2(pa.y + r.x, pa.w + r.y);  // log2 p(y=1) (shifted)
    float lz  = lse2_2(lo0, lo1);
    ((float2*)out)[idx] = make_float2((lo0 - lz) * LN2, (lo1 - lz) * LN2);
}

extern "C" void kernel_launch(void* const* d_in, const int* in_sizes, int n_in,
                              void* d_out, int out_size, void* d_ws, size_t ws_size,
                              hipStream_t stream) {
    const int* corr    = (const int*)d_in[0];
    const int* kc      = (const int*)d_in[1];
    const float* A     = (const float*)d_in[2];
    const float* trans = (const float*)d_in[3];
    const float* obs   = (const float*)d_in[4];
    const float* init  = (const float*)d_in[5];
    float* out = (float*)d_out;

    float* PA = (float*)d_ws;          // K*4 floats = 32 KB
    float* P3 = PA + KK * 4;           // K*2*4 floats = 64 KB (total 96 KB)

    precompute_P<<<KK, 64, 0, stream>>>(A, trans, obs, PA, P3);
    bkt_main<<<BB / 4, 64, 0, stream>>>(corr, kc, A, init, P3, out);
    finish_py<<<(BB * TT + 255) / 256, 256, 0, stream>>>(kc, PA, out);
}

// Round 9
// 82.182 us; speedup vs baseline: 1.1684x; 1.1684x over previous
//
#include <hip/hip_runtime.h>
#include <math.h>

#define BB 1024
#define TT 500
#define CC_ 64
#define KK 2000

#define LOG2E 1.44269504088896340736f
#define LN2   0.69314718055994530942f

typedef float f32x4 __attribute__((ext_vector_type(4)));
typedef float f32x2 __attribute__((ext_vector_type(2)));

// ---- fast hardware exp2/log2 (v_exp_f32 / v_log_f32) ----
#if __has_builtin(__builtin_amdgcn_exp2f)
__device__ __forceinline__ float fast_exp2(float x) { return __builtin_amdgcn_exp2f(x); }
#else
__device__ __forceinline__ float fast_exp2(float x) { return exp2f(x); }
#endif
#if __has_builtin(__builtin_amdgcn_logf)
__device__ __forceinline__ float fast_log2(float x) { return __builtin_amdgcn_logf(x); }
#else
__device__ __forceinline__ float fast_log2(float x) { return log2f(x); }
#endif

// max-guarded log2-sum-exp2 (off the hot loop)
__device__ __forceinline__ float lse2_2(float a, float b) {
    float m = fmaxf(a, b);
    float d = fminf(a, b) - m;              // <= 0
    return m + fast_log2(1.0f + fast_exp2(d));
}

// ---- DPP adds (VALU pipe, no LDS) ----
template<int CTRL, int RM, int BM>
__device__ __forceinline__ float dpp_add(float x) {
    int s = __builtin_amdgcn_update_dpp(0, __float_as_int(x), CTRL, RM, BM, true);
    return x + __int_as_float(s);
}
// full 64-lane sum into lane 63 (precompute only)
__device__ __forceinline__ float wave_sum63(float x) {
    x = dpp_add<0x111, 0xf, 0xf>(x);  // row_shr:1
    x = dpp_add<0x112, 0xf, 0xf>(x);  // row_shr:2
    x = dpp_add<0x114, 0xf, 0xf>(x);  // row_shr:4
    x = dpp_add<0x118, 0xf, 0xf>(x);  // row_shr:8
    x = dpp_add<0x142, 0xa, 0xf>(x);  // row_bcast15 (rows 1,3)
    x = dpp_add<0x143, 0xc, 0xf>(x);  // row_bcast31 (rows 2,3)
    return x;
}
// sum over the 16-lane DPP row; result in EVERY lane of the row (rotations)
__device__ __forceinline__ float rowsum16(float x) {
    x = dpp_add<0x121, 0xf, 0xf>(x);  // row_ror:1
    x = dpp_add<0x122, 0xf, 0xf>(x);  // row_ror:2
    x = dpp_add<0x124, 0xf, 0xf>(x);  // row_ror:4
    x = dpp_add<0x128, 0xf, 0xf>(x);  // row_ror:8
    return x;
}

// Precompute per-k tables (log2 units):
//   PA[k]    = {a1[0][0], a1[0][1], a1[1][0], a1[1][1]}         (for finish_py)
//   P3[k][y] = {2^(sel0+q00), 2^(sel0+q10), sel1+q01, sel1+q11} (for bkt_main)
__global__ __launch_bounds__(64) void precompute_P(
    const float* __restrict__ A,
    const float* __restrict__ trans_logits,
    const float* __restrict__ obs_logits,
    float* __restrict__ PA,
    float* __restrict__ P3)
{
    int k = blockIdx.x;
    int c = threadIdx.x;  // 0..63

    float ob[2][2];
#pragma unroll
    for (int s = 0; s < 2; ++s) {
        float o0 = obs_logits[c * 4 + s * 2 + 0] * LOG2E;
        float o1 = obs_logits[c * 4 + s * 2 + 1] * LOG2E;
        float l = lse2_2(o0, o1);
        ob[s][0] = o0 - l;
        ob[s][1] = o1 - l;
    }
    float lt[2][2];
    {
        float t00 = trans_logits[c * 4 + 0] * LOG2E;
        float t01 = trans_logits[c * 4 + 1] * LOG2E;
        float t10 = trans_logits[c * 4 + 2] * LOG2E;
        float t11 = trans_logits[c * 4 + 3] * LOG2E;
        float l0 = lse2_2(t00, t10);  // normalize over s (axis=1), u=0
        float l1 = lse2_2(t01, t11);  // u=1
        lt[0][0] = t00 - l0; lt[0][1] = t01 - l1;
        lt[1][0] = t10 - l0; lt[1][1] = t11 - l1;
    }

    float a = A[k * CC_ + c];
    float v[8];
    v[0] = a * ob[0][0]; v[1] = a * ob[0][1];
    v[2] = a * ob[1][0]; v[3] = a * ob[1][1];
    v[4] = a * lt[0][0]; v[5] = a * lt[0][1];
    v[6] = a * lt[1][0]; v[7] = a * lt[1][1];

#pragma unroll
    for (int i = 0; i < 8; ++i) v[i] = wave_sum63(v[i]);
    if (c == 63) {
        ((float4*)PA)[k] = make_float4(v[0], v[1], v[2], v[3]);
#pragma unroll
        for (int y = 0; y < 2; ++y) {
            float sel0 = v[y];      // a1[0][y]
            float sel1 = v[2 + y];  // a1[1][y]
            ((float4*)P3)[k * 2 + y] = make_float4(
                fast_exp2(sel0 + v[4]),   // E0 = 2^(sel0+q00)
                fast_exp2(sel0 + v[6]),   // E1 = 2^(sel0+q10)
                sel1 + v[5],              // v0 = sel1+q01
                sel1 + v[7]);             // v1 = sel1+q11
        }
    }
}

// Serial forward pass, 4 batches per wave (group g = lane>>4, lane i = lane&15
// holds chains 4i..4i+3). ROUND 9: fully manual VMEM pipeline in inline asm —
// the HIP scheduler provably collapsed the source-level rings (VGPR stayed 56
// across R6-R8; every step ate a ~200cy L2 round trip, VALUBusy 13%). All
// in-loop memory ops are asm volatile (fixed order, compiler cannot sink):
// per step: 2x global_load_dword (k,y for t+16), 2x global_load_dwordx4
// (A-row & P3-row for t+6), s_waitcnt vmcnt(30) (5 ops/step x 6 steps in
// flight; NEVER 0), compute, global_store_dwordx2. Consumed ring slots are
// tied "+v" to the waitcnt asm = data dependency, so VALU cannot hoist above
// the wait (rule #18 without relying on sched_barrier). Uniform SGPR bases +
// per-lane 32-bit voffsets.
__global__ __launch_bounds__(64, 1) void bkt_main(
    const int* __restrict__ corr,
    const int* __restrict__ kc,
    const float* __restrict__ A,
    const float* __restrict__ init_logits,
    const float* __restrict__ P3,
    float* __restrict__ out)
{
    int lane = threadIdx.x;
    int g = lane >> 4, i = lane & 15;
    int b = blockIdx.x * 4 + g;
    int bTT = b * TT;

    float la[4][2];
#pragma unroll
    for (int j = 0; j < 4; ++j) {
        float i0 = init_logits[(4 * i + j) * 2 + 0] * LOG2E;
        float i1 = init_logits[(4 * i + j) * 2 + 1] * LOG2E;
        float l = lse2_2(i0, i1);
        la[j][0] = i0 - l;
        la[j][1] = i1 - l;
    }

    int   kq[16], yq[16];   // k/y ring: slot j holds step t with t=j (mod 16)
    f32x4 ccq[8], pq[8];    // A-row / P3-row ring: slot t&7

    // ---- prologue: fill ky ring (steps 0..15), then A/P3 for steps 0..5 ----
#pragma unroll
    for (int q = 0; q < 16; ++q) {
        int voff = (bTT + q) * 4;
        asm volatile("global_load_dword %0, %2, %3\n\t"
                     "global_load_dword %1, %2, %4"
                     : "=&v"(kq[q]), "=&v"(yq[q])
                     : "v"(voff), "s"(kc), "s"(corr));
    }
#pragma unroll
    for (int q = 0; q < 16; ++q)
        asm volatile("s_waitcnt vmcnt(0)" : "+v"(kq[q]), "+v"(yq[q]));
#pragma unroll
    for (int q = 0; q < 6; ++q) {
        int va = kq[q] * 256 + i * 16;             // A + k*64 floats + lane slice
        int vp = (kq[q] * 2 + yq[q]) * 16;         // P3 + (k*2+y) float4
        asm volatile("global_load_dwordx4 %0, %1, %2"
                     : "=&v"(ccq[q]) : "v"(va), "s"(A));
        asm volatile("global_load_dwordx4 %0, %1, %2"
                     : "=&v"(pq[q]) : "v"(vp), "s"(P3));
    }
#pragma unroll
    for (int q = 0; q < 6; ++q)
        asm volatile("s_waitcnt vmcnt(0)" : "+v"(ccq[q]), "+v"(pq[q]));

    // ---- main loop: 32 x 16 = 512 steps; t=500..511 phantoms (loads clamped,
    // store skipped, la garbage discarded) ----
    for (int tt = 0; tt <= 496; tt += 16) {
#pragma unroll
        for (int j = 0; j < 16; ++j) {
            int t = tt + j;
            // ops 1,2: k/y for step t+16 into slot j (old content dead since t-6)
            int t16 = t + 16; if (t16 > TT - 1) t16 = TT - 1;
            int voff = (bTT + t16) * 4;
            asm volatile("global_load_dword %0, %2, %3\n\t"
                         "global_load_dword %1, %2, %4"
                         : "=&v"(kq[j]), "=&v"(yq[j])
                         : "v"(voff), "s"(kc), "s"(corr));
            // ops 3,4: A-row & P3-row for step t+6 (k/y guaranteed by wait t-1)
            int k6 = kq[(j + 6) & 15], y6 = yq[(j + 6) & 15];
            int va = k6 * 256 + i * 16;
            int vp = (k6 * 2 + y6) * 16;
            asm volatile("global_load_dwordx4 %0, %1, %2"
                         : "=&v"(ccq[(j + 6) & 7]) : "v"(va), "s"(A));
            asm volatile("global_load_dwordx4 %0, %1, %2"
                         : "=&v"(pq[(j + 6) & 7]) : "v"(vp), "s"(P3));
            // wait: completes through step t-6's P3 load (5 ops/step x 6 steps
            // = 30 newer ops stay in flight). Ties = data deps for consumers.
            asm volatile("s_waitcnt vmcnt(30)"
                         : "+v"(ccq[j & 7]), "+v"(pq[j & 7]),
                           "+v"(kq[(j + 7) & 15]), "+v"(yq[(j + 7) & 15]));

            f32x4 cc = ccq[j & 7];
            f32x4 pr = pq[j & 7];

            // r[s] = sum_c A[k,c]*la[c,s]: in-lane tree + 4 DPP rors
            float x0 = (cc.x * la[0][0] + cc.y * la[1][0])
                     + (cc.z * la[2][0] + cc.w * la[3][0]);
            float x1 = (cc.x * la[0][1] + cc.y * la[1][1])
                     + (cc.z * la[2][1] + cc.w * la[3][1]);
            x0 = rowsum16(x0);
            x1 = rowsum16(x1);

            // tail: only d = r1-r0 enters; E/v precomputed per (k,y)
            float d   = x1 - x0;
            float a30 = fast_log2(pr.x + fast_exp2(pr.z + d));  // a3[0]-r0
            float a31 = fast_log2(pr.y + fast_exp2(pr.w + d));  // a3[1]-r0
            // la_new = (1-cc)*(la - r0) + cc*a3'  (renorm by -r0 built in)
            {
                float g0, g1;
                g0 = la[0][0] - x0; g1 = la[0][1] - x0;
                la[0][0] = g0 + cc.x * (a30 - g0);
                la[0][1] = g1 + cc.x * (a31 - g1);
                g0 = la[1][0] - x0; g1 = la[1][1] - x0;
                la[1][0] = g0 + cc.y * (a30 - g0);
                la[1][1] = g1 + cc.y * (a31 - g1);
                g0 = la[2][0] - x0; g1 = la[2][1] - x0;
                la[2][0] = g0 + cc.z * (a30 - g0);
                la[2][1] = g1 + cc.z * (a31 - g1);
                g0 = la[3][0] - x0; g1 = la[3][1] - x0;
                la[3][0] = g0 + cc.w * (a30 - g0);
                la[3][1] = g1 + cc.w * (a31 - g1);
            }

            // op 5: store (x0,x1); identical across the 16 lanes of the group
            // (rowsum16 leaves the full sum in every lane) -> redundant same-
            // address stores are benign. Skipped in phantom steps (waits only
            // get stronger after that).
            if (t < TT) {
                f32x2 o; o.x = x0; o.y = x1;
                int vo = (bTT + t) * 8;
                asm volatile("global_store_dwordx2 %1, %0, %2"
                             :: "v"(o), "v"(vo), "s"(out));
            }
        }
    }
}

// Fully parallel epilogue: stored (r0,r1) -> log-softmax'd output (nat-log).
__global__ __launch_bounds__(256) void finish_py(
    const int* __restrict__ kc,
    const float* __restrict__ PA,
    float* __restrict__ out)
{
    int idx = blockIdx.x * 256 + threadIdx.x;  // idx = b*TT + t
    if (idx >= BB * TT) return;
    int k = kc[idx];
    float2 r  = ((const float2*)out)[idx];
    float4 pa = ((const float4*)PA)[k];
    float lo0 = lse2_2(pa.x + r.x, pa.z + r.y);  // log2 p(y=0) (shifted)
    float lo1 = lse2_2(pa.y + r.x, pa.w + r.y);  // log2 p(y=1) (shifted)
    float lz  = lse2_2(lo0, lo1);
    ((float2*)out)[idx] = make_float2((lo0 - lz) * LN2, (lo1 - lz) * LN2);
}

extern "C" void kernel_launch(void* const* d_in, const int* in_sizes, int n_in,
                              void* d_out, int out_size, void* d_ws, size_t ws_size,
                              hipStream_t stream) {
    const int* corr    = (const int*)d_in[0];
    const int* kc      = (const int*)d_in[1];
    const float* A     = (const float*)d_in[2];
    const float* trans = (const float*)d_in[3];
    const float* obs   = (const float*)d_in[4];
    const float* init  = (const float*)d_in[5];
    float* out = (float*)d_out;

    float* PA = (float*)d_ws;          // K*4 floats = 32 KB
    float* P3 = PA + KK * 4;           // K*2*4 floats = 64 KB (total 96 KB)

    precompute_P<<<KK, 64, 0, stream>>>(A, trans, obs, PA, P3);
    bkt_main<<<BB / 4, 64, 0, stream>>>(corr, kc, A, init, P3, out);
    finish_py<<<(BB * TT + 255) / 256, 256, 0, stream>>>(kc, PA, out);
}